// Round 3
// baseline (612.133 us; speedup 1.0000x reference)
//
#include <hip/hip_runtime.h>
#include <stdint.h>
#include <stddef.h>

// B=16, S=512, D=256, L=8192, DROP_P=0.2
#define B_ 16
#define S_ 512
#define D_ 256
#define L_ 8192

typedef unsigned short u16;
typedef _Float16 f16;
typedef f16 f16x4 __attribute__((ext_vector_type(4)));
typedef f16 f16x8 __attribute__((ext_vector_type(8)));   // MFMA A/B frag (4 VGPRs)
typedef float f32x4 __attribute__((ext_vector_type(4))); // MFMA C/D frag

// ---------------------------------------------------------------------------
// async global -> LDS, 16B/lane. LDS dest = wave-uniform base + lane*16.
// ---------------------------------------------------------------------------
__device__ __forceinline__ void gl16(const void* g, void* l) {
  __builtin_amdgcn_global_load_lds(
      (const __attribute__((address_space(1))) unsigned int*)g,
      (__attribute__((address_space(3))) unsigned int*)l, 16, 0, 0);
}

// ---------------------------------------------------------------------------
// JAX threefry2x32 dropout, key=(0,42), partitionable (bit-exact, r1-verified)
// ---------------------------------------------------------------------------
__device__ __forceinline__ uint32_t rotl32(uint32_t x, int r) {
  return (x << r) | (x >> (32 - r));
}
__device__ __forceinline__ bool drop_keep(uint32_t j) {
  const uint32_t k0 = 0u, k1 = 42u, k2 = 0x1BD11BDAu ^ k0 ^ k1;
  uint32_t v0 = 0u + k0;
  uint32_t v1 = j + k1;
#define TF_R(r) { v0 += v1; v1 = rotl32(v1, (r)); v1 ^= v0; }
  TF_R(13) TF_R(15) TF_R(26) TF_R(6)
  v0 += k1; v1 += k2 + 1u;
  TF_R(17) TF_R(29) TF_R(16) TF_R(24)
  v0 += k2; v1 += k0 + 2u;
  TF_R(13) TF_R(15) TF_R(26) TF_R(6)
  v0 += k0; v1 += k1 + 3u;
  TF_R(17) TF_R(29) TF_R(16) TF_R(24)
  v0 += k1; v1 += k2 + 4u;
  TF_R(13) TF_R(15) TF_R(26) TF_R(6)
  v0 += k2; v1 += k0 + 5u;
#undef TF_R
  uint32_t bits = v0 ^ v1;
  float u = __uint_as_float((bits >> 9) | 0x3f800000u) - 1.0f;
  return u < 0.8f;
}

// ---------------------------------------------------------------------------
// prep: fp32 -> fp16 convert (8 elem/thread)
// ---------------------------------------------------------------------------
__global__ __launch_bounds__(256)
void conv16_kernel(const float* __restrict__ src, f16* __restrict__ dst, int n) {
  int i = (blockIdx.x * 256 + threadIdx.x) * 8;
  if (i >= n) return;
  float4 a = *(const float4*)&src[i];
  float4 b = *(const float4*)&src[i + 4];
  f16x8 o;
  o[0] = (f16)a.x; o[1] = (f16)a.y; o[2] = (f16)a.z; o[3] = (f16)a.w;
  o[4] = (f16)b.x; o[5] = (f16)b.y; o[6] = (f16)b.z; o[7] = (f16)b.w;
  *(f16x8*)&dst[i] = o;
}

// x [B][S][D] fp32 -> xT [B][D][S] fp16
__global__ __launch_bounds__(256)
void xt16_kernel(const float* __restrict__ x, f16* __restrict__ xT) {
  const int b = blockIdx.z, sb = blockIdx.x * 32, db = blockIdx.y * 32;
  __shared__ float t[32][33];
  const int tid = threadIdx.x;
  const int r = tid >> 3, c4 = (tid & 7) * 4;
  float4 v = *(const float4*)&x[((size_t)b * S_ + sb + r) * D_ + db + c4];
  t[r][c4] = v.x; t[r][c4 + 1] = v.y; t[r][c4 + 2] = v.z; t[r][c4 + 3] = v.w;
  __syncthreads();
  const int dr = tid >> 3, s4 = (tid & 7) * 4;
  f16x4 o;
#pragma unroll
  for (int j = 0; j < 4; ++j) o[j] = (f16)t[s4 + j][dr];
  *(f16x4*)&xT[((size_t)b * D_ + db + dr) * S_ + sb + s4] = o;
}

// ---------------------------------------------------------------------------
// GEMM1T (fp16 MFMA): scoresT[b, lt+l, st+s] = E[l,:] . x[s,:]  (fp32 out)
// Bit-identical to old scores (operand swap transposes D; same k order).
// Tile 128l x 128s, BK=32, 4 waves (2m x 2n), granule-major LDS
// (conflict-free b128 frag reads), 2-phase double-buffered staging.
// Epilogue: per-s column max/expsum over l -> partials.
// ---------------------------------------------------------------------------
__global__ __launch_bounds__(256)
void gemm1t_f16(const f16* __restrict__ eh, const f16* __restrict__ xh,
                float* __restrict__ scoresT, float2* __restrict__ partials) {
  __shared__ __align__(16) f16 As[2][4096];  // E tile, granule = kq*128 + l
  __shared__ __align__(16) f16 Bs[2][4096];  // x tile, granule = kq*128 + s
  __shared__ float pmaxA[128][2];
  __shared__ float psumA[128][2];

  const int tid = threadIdx.x;
  const int lane = tid & 63, wave = tid >> 6;
  const int b = blockIdx.z, lt = blockIdx.x * 128, st = blockIdx.y * 128;

  const int lm = lane & 15, kq = lane >> 4;
  const int wm = (wave & 1) * 64, wn = (wave >> 1) * 64;

  // staging: wave w stages chunks {2w, 2w+1} of A and of B.
  // chunk c (0..7): kqc = c>>1, row-block = (c&1)*64; granule = c*64 + lane.
  const int c0 = wave * 2;
  auto stage = [&](int bi, int k0) {
#pragma unroll
    for (int i = 0; i < 2; ++i) {
      const int c = c0 + i, kqc = c >> 1, rb = (c & 1) * 64;
      gl16(eh + ((size_t)b * L_ + lt + rb + lane) * D_ + k0 + kqc * 8,
           (char*)As[bi] + c * 1024 + lane * 16);
      gl16(xh + ((size_t)b * S_ + st + rb + lane) * D_ + k0 + kqc * 8,
           (char*)Bs[bi] + c * 1024 + lane * 16);
    }
  };

  f32x4 acc[4][4] = {};

  stage(0, 0);
  __syncthreads();
  int bi = 0;
  for (int t = 0; t < 8; ++t) {
    if (t < 7) stage(bi ^ 1, (t + 1) * 32);
    f16x8 fa[4], fb[4];
#pragma unroll
    for (int mi = 0; mi < 4; ++mi)
      fa[mi] = *(const f16x8*)&As[bi][(kq * 128 + wm + mi * 16 + lm) * 8];
#pragma unroll
    for (int ni = 0; ni < 4; ++ni)
      fb[ni] = *(const f16x8*)&Bs[bi][(kq * 128 + wn + ni * 16 + lm) * 8];
#pragma unroll
    for (int mi = 0; mi < 4; ++mi)
#pragma unroll
      for (int ni = 0; ni < 4; ++ni)
        acc[mi][ni] = __builtin_amdgcn_mfma_f32_16x16x32_f16(
            fa[mi], fb[ni], acc[mi][ni], 0, 0, 0);
    __syncthreads();
    bi ^= 1;
  }

  // ---- scoresT store. D: row l = kq*4 + r (within 16-tile), col s = lm ----
#pragma unroll
  for (int mi = 0; mi < 4; ++mi)
#pragma unroll
    for (int ni = 0; ni < 4; ++ni) {
      const int l0 = wm + mi * 16 + kq * 4;
      const int s = wn + ni * 16 + lm;
      float* sp = scoresT + ((size_t)b * L_ + lt + l0) * S_ + st + s;
#pragma unroll
      for (int r = 0; r < 4; ++r) sp[(size_t)r * S_] = acc[mi][ni][r];
    }

  // ---- per-s column max over this wave's 64 l-rows ----
  float cmax[4];
#pragma unroll
  for (int ni = 0; ni < 4; ++ni) {
    float v = acc[0][ni][0];
#pragma unroll
    for (int mi = 0; mi < 4; ++mi)
#pragma unroll
      for (int r = 0; r < 4; ++r) v = fmaxf(v, acc[mi][ni][r]);
    cmax[ni] = v;
  }
#pragma unroll
  for (int ni = 0; ni < 4; ++ni) {
    cmax[ni] = fmaxf(cmax[ni], __shfl_xor(cmax[ni], 16, 64));
    cmax[ni] = fmaxf(cmax[ni], __shfl_xor(cmax[ni], 32, 64));
  }
  if (kq == 0) {
#pragma unroll
    for (int ni = 0; ni < 4; ++ni) pmaxA[wn + ni * 16 + lm][wave & 1] = cmax[ni];
  }
  __syncthreads();
  float colm[4];
#pragma unroll
  for (int ni = 0; ni < 4; ++ni) {
    const int s = wn + ni * 16 + lm;
    colm[ni] = fmaxf(pmaxA[s][0], pmaxA[s][1]);
  }
  float psum[4] = {};
#pragma unroll
  for (int ni = 0; ni < 4; ++ni)
#pragma unroll
    for (int mi = 0; mi < 4; ++mi)
#pragma unroll
      for (int r = 0; r < 4; ++r)
        psum[ni] += __expf(acc[mi][ni][r] - colm[ni]);
#pragma unroll
  for (int ni = 0; ni < 4; ++ni) {
    psum[ni] += __shfl_xor(psum[ni], 16, 64);
    psum[ni] += __shfl_xor(psum[ni], 32, 64);
  }
  if (kq == 0) {
#pragma unroll
    for (int ni = 0; ni < 4; ++ni) psumA[wn + ni * 16 + lm][wave & 1] = psum[ni];
  }
  __syncthreads();
  if (tid < 128) {
    float m = fmaxf(pmaxA[tid][0], pmaxA[tid][1]);
    float Z = psumA[tid][0] + psumA[tid][1];
    partials[((size_t)b * 64 + blockIdx.x) * S_ + st + tid] = make_float2(m, Z);
  }
}

// ---------------------------------------------------------------------------
// combine partial (m,Z) over 64 l-tiles -> stats (m, factor)
// ---------------------------------------------------------------------------
__global__ __launch_bounds__(256)
void combine_kernel(const float2* __restrict__ partials,
                    const int* __restrict__ mask, float2* __restrict__ stats) {
  const int idx = blockIdx.x * 256 + threadIdx.x;  // b*S + si
  const int b = idx / S_, si = idx - b * S_;
  float m = -3.402823466e38f, Z = 0.f;
  for (int t = 0; t < 64; ++t) {
    float2 p = partials[((size_t)b * 64 + t) * S_ + si];
    if (p.x > m) {
      Z = Z * __expf(m - p.x) + p.y;
      m = p.x;
    } else {
      Z += p.y * __expf(p.x - m);
    }
  }
  float f = (mask[idx] != 0) ? (1.25f / Z) : 0.0f;
  stats[idx] = make_float2(m, f);
}

// ---------------------------------------------------------------------------
// GEMM2 fused (fp16 MFMA, full-D tile, K = S = 512):
//   out[b, lt+l, d] = sum_s P(s, lt+l) * x[s, d]
// P computed on the fly from scoresT tile in LDS. Granule-major LDS layouts
// (conflict-free f32x4 / f16x8 frag reads), 2-phase double-buffered staging.
// 512 threads = 8 waves; wave w owns l-rows [w*16, w*16+16), all 256 d.
// ---------------------------------------------------------------------------
__global__ __launch_bounds__(512)
void gemm2_fused(const float* __restrict__ scoresT, const f16* __restrict__ xT,
                 const float2* __restrict__ stats, float* __restrict__ out) {
  __shared__ __align__(16) float Ss[2][4096];  // scoresT tile, granule = gs*128 + l
  __shared__ __align__(16) f16 Bs[2][8192];    // xT tile, granule = kq*256 + d
  __shared__ float2 stat_s[S_];                // 4 KB, full-S stats

  const int tid = threadIdx.x;
  const int lane = tid & 63, wave = tid >> 6;
  const int b = blockIdx.z, lt = blockIdx.x * 128;

  stat_s[tid] = stats[b * S_ + tid];  // covered by prologue barrier

  const int lm = lane & 15, kq = lane >> 4;
  const int l_loc = wave * 16 + lm;  // 0..127
  const uint32_t gbase =
      (uint32_t)(b * S_) * (uint32_t)L_ + (uint32_t)(lt + l_loc);

  // staging: wave w stages chunks {2w, 2w+1} of Ss (c 0..15) and Bs (c 0..15).
  // Ss chunk c: gs = c>>1, l-block = (c&1)*64 ; granule = c*64 + lane.
  // Bs chunk c: kqc = c>>2, d-block = (c&3)*64 ; granule = c*64 + lane.
  const int c0 = wave * 2;
  auto stage = [&](int bi, int k0) {
#pragma unroll
    for (int i = 0; i < 2; ++i) {
      const int c = c0 + i;
      {
        const int gs = c >> 1, lb = (c & 1) * 64;
        gl16(scoresT + ((size_t)b * L_ + lt + lb + lane) * S_ + k0 + gs * 4,
             (char*)Ss[bi] + c * 1024 + lane * 16);
      }
      {
        const int kqc = c >> 2, db = (c & 3) * 64;
        gl16(xT + ((size_t)b * D_ + db + lane) * S_ + k0 + kqc * 8,
             (char*)Bs[bi] + c * 1024 + lane * 16);
      }
    }
  };

  f32x4 acc[16] = {};

  stage(0, 0);
  __syncthreads();
  int bi = 0;
  for (int k0 = 0; k0 < S_; k0 += 32) {
    if (k0 < S_ - 32) stage(bi ^ 1, k0 + 32);

    // P-source: lane's own l-row, s = k0 + kq*8 .. +7 (two f32x4 reads)
    const f32x4 v0 = *(const f32x4*)&Ss[bi][((kq * 2 + 0) * 128 + l_loc) * 4];
    const f32x4 v1 = *(const f32x4*)&Ss[bi][((kq * 2 + 1) * 128 + l_loc) * 4];
    float pv[8];
#pragma unroll
    for (int j = 0; j < 4; ++j) {
      const float2 mf = stat_s[k0 + kq * 8 + j];
      pv[j] = __expf(v0[j] - mf.x) * mf.y;
    }
#pragma unroll
    for (int j = 0; j < 4; ++j) {
      const float2 mf = stat_s[k0 + kq * 8 + 4 + j];
      pv[4 + j] = __expf(v1[j] - mf.x) * mf.y;
    }
    f16x8 fa;
#pragma unroll
    for (int j = 0; j < 8; ++j) {
      const uint32_t gidx = gbase + (uint32_t)(k0 + kq * 8 + j) * (uint32_t)L_;
      fa[j] = drop_keep(gidx) ? (f16)pv[j] : (f16)0.f;
    }

#pragma unroll
    for (int ni = 0; ni < 16; ++ni) {
      const f16x8 fb = *(const f16x8*)&Bs[bi][(kq * 256 + ni * 16 + lm) * 8];
      acc[ni] = __builtin_amdgcn_mfma_f32_16x16x32_f16(fa, fb, acc[ni], 0, 0, 0);
    }
    __syncthreads();
    bi ^= 1;
  }

  // ---- epilogue. C/D: col = lane&15 (d), row = kq*4 + reg (l within 16) ----
#pragma unroll
  for (int ni = 0; ni < 16; ++ni) {
    const int n = ni * 16 + lm;
    float* op = out + ((size_t)b * L_ + lt + wave * 16 + kq * 4) * D_ + n;
#pragma unroll
    for (int r = 0; r < 4; ++r) op[(size_t)r * D_] = acc[ni][r];
  }
}

// ---------------------------------------------------------------------------
extern "C" void kernel_launch(void* const* d_in, const int* in_sizes, int n_in,
                              void* d_out, int out_size, void* d_ws, size_t ws_size,
                              hipStream_t stream) {
  const float* x = (const float*)d_in[0];
  const int* mask = (const int*)d_in[1];
  const float* E = (const float*)d_in[2];
  float* out = (float*)d_out;

  char* ws = (char*)d_ws;
  const size_t nE = (size_t)B_ * L_ * D_;  // 33.5M
  const size_t nX = (size_t)B_ * S_ * D_;  // 2.1M
  size_t o = 0;
  f16* Eh = (f16*)(ws + o); o += nE * 2;                                // 67 MB
  f16* Xh = (f16*)(ws + o); o += nX * 2;                                // 4 MB
  f16* XT = (f16*)(ws + o); o += nX * 2;                                // 4 MB
  float2* stats = (float2*)(ws + o); o += (size_t)B_ * S_ * 8;          // 64 KB
  float2* partials = (float2*)(ws + o); o += (size_t)B_ * 64 * S_ * 8;  // 4 MB
  float* scoresT = (float*)(ws + o);  // [B][L][S] fp32, 268 MB (total ~343 MB)

  conv16_kernel<<<dim3((unsigned)(nE / 8 / 256)), 256, 0, stream>>>(E, Eh, (int)nE);
  conv16_kernel<<<dim3((unsigned)(nX / 8 / 256)), 256, 0, stream>>>(x, Xh, (int)nX);
  xt16_kernel<<<dim3(S_ / 32, D_ / 32, B_), 256, 0, stream>>>(x, XT);

  gemm1t_f16<<<dim3(L_ / 128, S_ / 128, B_), 256, 0, stream>>>(
      Eh, Xh, scoresT, partials);
  combine_kernel<<<dim3(B_ * S_ / 256), 256, 0, stream>>>(partials, mask, stats);
  gemm2_fused<<<dim3(L_ / 128, 1, B_), 512, 0, stream>>>(scoresT, XT, stats, out);
}

// Round 4
// 571.723 us; speedup vs baseline: 1.0707x; 1.0707x over previous
//
#include <hip/hip_runtime.h>
#include <stdint.h>
#include <stddef.h>

// B=16, S=512, D=256, L=8192, DROP_P=0.2
#define B_ 16
#define S_ 512
#define D_ 256
#define L_ 8192

typedef unsigned short u16;
typedef _Float16 f16;
typedef f16 f16x4 __attribute__((ext_vector_type(4)));
typedef f16 f16x8 __attribute__((ext_vector_type(8)));   // MFMA A/B frag (4 VGPRs)
typedef float f32x4 __attribute__((ext_vector_type(4))); // MFMA C/D frag

// ---------------------------------------------------------------------------
// async global -> LDS, 16B/lane. LDS dest = wave-uniform base + lane*16.
// ---------------------------------------------------------------------------
__device__ __forceinline__ void gl16(const void* g, void* l) {
  __builtin_amdgcn_global_load_lds(
      (const __attribute__((address_space(1))) unsigned int*)g,
      (__attribute__((address_space(3))) unsigned int*)l, 16, 0, 0);
}

// ---------------------------------------------------------------------------
// JAX threefry2x32 dropout, key=(0,42), partitionable (bit-exact, r1-verified)
// ---------------------------------------------------------------------------
__device__ __forceinline__ uint32_t rotl32(uint32_t x, int r) {
  return (x << r) | (x >> (32 - r));
}
__device__ __forceinline__ bool drop_keep(uint32_t j) {
  const uint32_t k0 = 0u, k1 = 42u, k2 = 0x1BD11BDAu ^ k0 ^ k1;
  uint32_t v0 = 0u + k0;
  uint32_t v1 = j + k1;
#define TF_R(r) { v0 += v1; v1 = rotl32(v1, (r)); v1 ^= v0; }
  TF_R(13) TF_R(15) TF_R(26) TF_R(6)
  v0 += k1; v1 += k2 + 1u;
  TF_R(17) TF_R(29) TF_R(16) TF_R(24)
  v0 += k2; v1 += k0 + 2u;
  TF_R(13) TF_R(15) TF_R(26) TF_R(6)
  v0 += k0; v1 += k1 + 3u;
  TF_R(17) TF_R(29) TF_R(16) TF_R(24)
  v0 += k1; v1 += k2 + 4u;
  TF_R(13) TF_R(15) TF_R(26) TF_R(6)
  v0 += k2; v1 += k0 + 5u;
#undef TF_R
  uint32_t bits = v0 ^ v1;
  float u = __uint_as_float((bits >> 9) | 0x3f800000u) - 1.0f;
  return u < 0.8f;
}

// ---------------------------------------------------------------------------
// prep: fp32 -> fp16 convert (8 elem/thread)
// ---------------------------------------------------------------------------
__global__ __launch_bounds__(256)
void conv16_kernel(const float* __restrict__ src, f16* __restrict__ dst, int n) {
  int i = (blockIdx.x * 256 + threadIdx.x) * 8;
  if (i >= n) return;
  float4 a = *(const float4*)&src[i];
  float4 b = *(const float4*)&src[i + 4];
  f16x8 o;
  o[0] = (f16)a.x; o[1] = (f16)a.y; o[2] = (f16)a.z; o[3] = (f16)a.w;
  o[4] = (f16)b.x; o[5] = (f16)b.y; o[6] = (f16)b.z; o[7] = (f16)b.w;
  *(f16x8*)&dst[i] = o;
}

// x [B][S][D] fp32 -> xT [B][D][S] fp16
__global__ __launch_bounds__(256)
void xt16_kernel(const float* __restrict__ x, f16* __restrict__ xT) {
  const int b = blockIdx.z, sb = blockIdx.x * 32, db = blockIdx.y * 32;
  __shared__ float t[32][33];
  const int tid = threadIdx.x;
  const int r = tid >> 3, c4 = (tid & 7) * 4;
  float4 v = *(const float4*)&x[((size_t)b * S_ + sb + r) * D_ + db + c4];
  t[r][c4] = v.x; t[r][c4 + 1] = v.y; t[r][c4 + 2] = v.z; t[r][c4 + 3] = v.w;
  __syncthreads();
  const int dr = tid >> 3, s4 = (tid & 7) * 4;
  f16x4 o;
#pragma unroll
  for (int j = 0; j < 4; ++j) o[j] = (f16)t[s4 + j][dr];
  *(f16x4*)&xT[((size_t)b * D_ + db + dr) * S_ + sb + s4] = o;
}

// ---------------------------------------------------------------------------
// GEMM1T (fp16 MFMA): scoresT[b, lt+l, st+s] = E[l,:] . x[s,:]  (fp32 out)
// Tile 128l x 128s, BK=32, 4 waves (2m x 2n). Staging: 16-row x 64B chunks
// (coalesced address set) with lane permutation (kq' = lane>>4, row = lane&15)
// so the linear LDS dest is kq-major granules -> conflict-free b128 frag
// reads (granule%8 = row&7). 2-phase double-buffered.
// Epilogue: per-s column max/expsum over l -> partials.
// ---------------------------------------------------------------------------
__global__ __launch_bounds__(256)
void gemm1t_f16(const f16* __restrict__ eh, const f16* __restrict__ xh,
                float* __restrict__ scoresT, float2* __restrict__ partials) {
  __shared__ __align__(16) f16 As[2][4096];  // E tile: granule = c*64+kq'*16+rlow
  __shared__ __align__(16) f16 Bs[2][4096];  // x tile: same layout
  __shared__ float pmaxA[128][2];
  __shared__ float psumA[128][2];

  const int tid = threadIdx.x;
  const int lane = tid & 63, wave = tid >> 6;
  const int b = blockIdx.z, lt = blockIdx.x * 128, st = blockIdx.y * 128;

  const int lm = lane & 15, kq = lane >> 4;
  const int wm = (wave & 1) * 64, wn = (wave >> 1) * 64;
  const int ca = (wave & 1) * 4, cb = (wave >> 1) * 4;  // frag chunk bases

  // staging lane mapping: row = 16c + (lane&15), k-slice = (lane>>4)*8 f16.
  const int srow = lane & 15, sko = (lane >> 4) * 8;
  auto stage = [&](int bi, int k0) {
#pragma unroll
    for (int i = 0; i < 2; ++i) {
      const int c = wave * 2 + i;
      gl16(eh + ((size_t)b * L_ + lt + c * 16 + srow) * D_ + k0 + sko,
           (char*)As[bi] + c * 1024 + lane * 16);
      gl16(xh + ((size_t)b * S_ + st + c * 16 + srow) * D_ + k0 + sko,
           (char*)Bs[bi] + c * 1024 + lane * 16);
    }
  };

  f32x4 acc[4][4] = {};

  stage(0, 0);
  __syncthreads();
  int bi = 0;
  for (int t = 0; t < 8; ++t) {
    if (t < 7) stage(bi ^ 1, (t + 1) * 32);
    f16x8 fa[4], fb[4];
#pragma unroll
    for (int mi = 0; mi < 4; ++mi)
      fa[mi] = *(const f16x8*)&As[bi][((ca + mi) * 64 + kq * 16 + lm) * 8];
#pragma unroll
    for (int ni = 0; ni < 4; ++ni)
      fb[ni] = *(const f16x8*)&Bs[bi][((cb + ni) * 64 + kq * 16 + lm) * 8];
#pragma unroll
    for (int mi = 0; mi < 4; ++mi)
#pragma unroll
      for (int ni = 0; ni < 4; ++ni)
        acc[mi][ni] = __builtin_amdgcn_mfma_f32_16x16x32_f16(
            fa[mi], fb[ni], acc[mi][ni], 0, 0, 0);
    __syncthreads();
    bi ^= 1;
  }

  // ---- scoresT store. D: row l = kq*4 + r (within 16-tile), col s = lm ----
#pragma unroll
  for (int mi = 0; mi < 4; ++mi)
#pragma unroll
    for (int ni = 0; ni < 4; ++ni) {
      const int l0 = wm + mi * 16 + kq * 4;
      const int s = wn + ni * 16 + lm;
      float* sp = scoresT + ((size_t)b * L_ + lt + l0) * S_ + st + s;
#pragma unroll
      for (int r = 0; r < 4; ++r) sp[(size_t)r * S_] = acc[mi][ni][r];
    }

  // ---- per-s column max over this wave's 64 l-rows ----
  float cmax[4];
#pragma unroll
  for (int ni = 0; ni < 4; ++ni) {
    float v = acc[0][ni][0];
#pragma unroll
    for (int mi = 0; mi < 4; ++mi)
#pragma unroll
      for (int r = 0; r < 4; ++r) v = fmaxf(v, acc[mi][ni][r]);
    cmax[ni] = v;
  }
#pragma unroll
  for (int ni = 0; ni < 4; ++ni) {
    cmax[ni] = fmaxf(cmax[ni], __shfl_xor(cmax[ni], 16, 64));
    cmax[ni] = fmaxf(cmax[ni], __shfl_xor(cmax[ni], 32, 64));
  }
  if (kq == 0) {
#pragma unroll
    for (int ni = 0; ni < 4; ++ni) pmaxA[wn + ni * 16 + lm][wave & 1] = cmax[ni];
  }
  __syncthreads();
  float colm[4];
#pragma unroll
  for (int ni = 0; ni < 4; ++ni) {
    const int s = wn + ni * 16 + lm;
    colm[ni] = fmaxf(pmaxA[s][0], pmaxA[s][1]);
  }
  float psum[4] = {};
#pragma unroll
  for (int ni = 0; ni < 4; ++ni)
#pragma unroll
    for (int mi = 0; mi < 4; ++mi)
#pragma unroll
      for (int r = 0; r < 4; ++r)
        psum[ni] += __expf(acc[mi][ni][r] - colm[ni]);
#pragma unroll
  for (int ni = 0; ni < 4; ++ni) {
    psum[ni] += __shfl_xor(psum[ni], 16, 64);
    psum[ni] += __shfl_xor(psum[ni], 32, 64);
  }
  if (kq == 0) {
#pragma unroll
    for (int ni = 0; ni < 4; ++ni) psumA[wn + ni * 16 + lm][wave & 1] = psum[ni];
  }
  __syncthreads();
  if (tid < 128) {
    float m = fmaxf(pmaxA[tid][0], pmaxA[tid][1]);
    float Z = psumA[tid][0] + psumA[tid][1];
    partials[((size_t)b * 64 + blockIdx.x) * S_ + st + tid] = make_float2(m, Z);
  }
}

// ---------------------------------------------------------------------------
// combine partial (m,Z) over 64 l-tiles -> stats (m, factor)
// ---------------------------------------------------------------------------
__global__ __launch_bounds__(256)
void combine_kernel(const float2* __restrict__ partials,
                    const int* __restrict__ mask, float2* __restrict__ stats) {
  const int idx = blockIdx.x * 256 + threadIdx.x;  // b*S + si
  const int b = idx / S_, si = idx - b * S_;
  float m = -3.402823466e38f, Z = 0.f;
  for (int t = 0; t < 64; ++t) {
    float2 p = partials[((size_t)b * 64 + t) * S_ + si];
    if (p.x > m) {
      Z = Z * __expf(m - p.x) + p.y;
      m = p.x;
    } else {
      Z += p.y * __expf(p.x - m);
    }
  }
  float f = (mask[idx] != 0) ? (1.25f / Z) : 0.0f;
  stats[idx] = make_float2(m, f);
}

// ---------------------------------------------------------------------------
// GEMM2 fused (fp16 MFMA, full-D tile, K = S = 512):
//   out[b, lt+l, d] = sum_s P(s, lt+l) * x[s, d]
// P computed on the fly. Scores: per-lane f32x4 pair straight from global
// (lane's own l-row, contiguous in s; prefetched one chunk ahead) — no LDS.
// Bs (xT): double-buffered, coalesced 16-row x 64B chunk staging with lane
// permutation -> kq-major granules, conflict-free f16x8 frag reads.
// LDS 36 KB -> 4 blocks/CU. 512 threads = 8 waves; wave owns 16 l-rows.
// ---------------------------------------------------------------------------
__global__ __launch_bounds__(512)
void gemm2_fused(const float* __restrict__ scoresT, const f16* __restrict__ xT,
                 const float2* __restrict__ stats, float* __restrict__ out) {
  __shared__ __align__(16) f16 Bs[2][8192];    // xT tile: granule = c*64+kq'*16+dlow
  __shared__ float2 stat_s[S_];                // 4 KB, full-S stats

  const int tid = threadIdx.x;
  const int lane = tid & 63, wave = tid >> 6;
  const int b = blockIdx.z, lt = blockIdx.x * 128;

  stat_s[tid] = stats[b * S_ + tid];  // covered by prologue barrier

  const int lm = lane & 15, kq = lane >> 4;
  const int l_loc = wave * 16 + lm;  // 0..127
  const uint32_t gbase =
      (uint32_t)(b * S_) * (uint32_t)L_ + (uint32_t)(lt + l_loc);

  // Bs staging: chunk c (0..15) = d-rows [16c,16c+16). lane -> d = 16c+(lane&15),
  // s-slice = (lane>>4)*8 f16. Wave w stages chunks {2w, 2w+1}.
  const int srow = lane & 15, sko = (lane >> 4) * 8;
  const size_t xb_base = (size_t)b * D_ * S_;
  auto stage = [&](int bi, int k0) {
#pragma unroll
    for (int i = 0; i < 2; ++i) {
      const int c = wave * 2 + i;
      gl16(xT + xb_base + (size_t)(c * 16 + srow) * S_ + k0 + sko,
           (char*)Bs[bi] + c * 1024 + lane * 16);
    }
  };

  // per-lane scores row pointer: contiguous 32 B (8 floats) per chunk
  const float* srowp =
      scoresT + ((size_t)b * L_ + lt + l_loc) * S_ + kq * 8;

  f32x4 acc[16] = {};

  f32x4 sv0 = *(const f32x4*)&srowp[0];
  f32x4 sv1 = *(const f32x4*)&srowp[4];
  stage(0, 0);
  __syncthreads();
  int bi = 0;
  for (int k0 = 0; k0 < S_; k0 += 32) {
    f32x4 nv0, nv1;
    const bool more = (k0 < S_ - 32);
    if (more) {
      stage(bi ^ 1, k0 + 32);
      nv0 = *(const f32x4*)&srowp[k0 + 32];
      nv1 = *(const f32x4*)&srowp[k0 + 36];
    }

    // ---- P values for s = k0 + kq*8 + (0..7) ----
    float pv[8];
#pragma unroll
    for (int j = 0; j < 4; ++j) {
      const float2 mf = stat_s[k0 + kq * 8 + j];
      pv[j] = __expf(sv0[j] - mf.x) * mf.y;
    }
#pragma unroll
    for (int j = 0; j < 4; ++j) {
      const float2 mf = stat_s[k0 + kq * 8 + 4 + j];
      pv[4 + j] = __expf(sv1[j] - mf.x) * mf.y;
    }
    f16x8 fa;
#pragma unroll
    for (int j = 0; j < 8; ++j) {
      const uint32_t gidx = gbase + (uint32_t)(k0 + kq * 8 + j) * (uint32_t)L_;
      fa[j] = drop_keep(gidx) ? (f16)pv[j] : (f16)0.f;
    }

#pragma unroll
    for (int ni = 0; ni < 16; ++ni) {
      const f16x8 fb = *(const f16x8*)&Bs[bi][(ni * 64 + kq * 16 + lm) * 8];
      acc[ni] = __builtin_amdgcn_mfma_f32_16x16x32_f16(fa, fb, acc[ni], 0, 0, 0);
    }
    __syncthreads();
    if (more) { sv0 = nv0; sv1 = nv1; }
    bi ^= 1;
  }

  // ---- epilogue. C/D: col = lane&15 (d), row = kq*4 + reg (l within 16) ----
#pragma unroll
  for (int ni = 0; ni < 16; ++ni) {
    const int n = ni * 16 + lm;
    float* op = out + ((size_t)b * L_ + lt + wave * 16 + kq * 4) * D_ + n;
#pragma unroll
    for (int r = 0; r < 4; ++r) op[(size_t)r * D_] = acc[ni][r];
  }
}

// ---------------------------------------------------------------------------
extern "C" void kernel_launch(void* const* d_in, const int* in_sizes, int n_in,
                              void* d_out, int out_size, void* d_ws, size_t ws_size,
                              hipStream_t stream) {
  const float* x = (const float*)d_in[0];
  const int* mask = (const int*)d_in[1];
  const float* E = (const float*)d_in[2];
  float* out = (float*)d_out;

  char* ws = (char*)d_ws;
  const size_t nE = (size_t)B_ * L_ * D_;  // 33.5M
  const size_t nX = (size_t)B_ * S_ * D_;  // 2.1M
  size_t o = 0;
  f16* Eh = (f16*)(ws + o); o += nE * 2;                                // 67 MB
  f16* Xh = (f16*)(ws + o); o += nX * 2;                                // 4 MB
  f16* XT = (f16*)(ws + o); o += nX * 2;                                // 4 MB
  float2* stats = (float2*)(ws + o); o += (size_t)B_ * S_ * 8;          // 64 KB
  float2* partials = (float2*)(ws + o); o += (size_t)B_ * 64 * S_ * 8;  // 4 MB
  float* scoresT = (float*)(ws + o);  // [B][L][S] fp32, 268 MB (total ~343 MB)

  conv16_kernel<<<dim3((unsigned)(nE / 8 / 256)), 256, 0, stream>>>(E, Eh, (int)nE);
  conv16_kernel<<<dim3((unsigned)(nX / 8 / 256)), 256, 0, stream>>>(x, Xh, (int)nX);
  xt16_kernel<<<dim3(S_ / 32, D_ / 32, B_), 256, 0, stream>>>(x, XT);

  gemm1t_f16<<<dim3(L_ / 128, S_ / 128, B_), 256, 0, stream>>>(
      Eh, Xh, scoresT, partials);
  combine_kernel<<<dim3(B_ * S_ / 256), 256, 0, stream>>>(partials, mask, stats);
  gemm2_fused<<<dim3(L_ / 128, 1, B_), 512, 0, stream>>>(scoresT, XT, stats, out);
}

// Round 5
// 523.724 us; speedup vs baseline: 1.1688x; 1.0916x over previous
//
#include <hip/hip_runtime.h>
#include <stdint.h>
#include <stddef.h>

// B=16, S=512, D=256, L=8192, DROP_P=0.2
#define B_ 16
#define S_ 512
#define D_ 256
#define L_ 8192

typedef unsigned short u16;
typedef _Float16 f16;
typedef f16 f16x4 __attribute__((ext_vector_type(4)));
typedef f16 f16x8 __attribute__((ext_vector_type(8)));   // MFMA A/B frag (4 VGPRs)
typedef float f32x4 __attribute__((ext_vector_type(4))); // MFMA C/D frag

// ---------------------------------------------------------------------------
// async global -> LDS, 16B/lane. LDS dest = wave-uniform base + lane*16.
// ---------------------------------------------------------------------------
__device__ __forceinline__ void gl16(const void* g, void* l) {
  __builtin_amdgcn_global_load_lds(
      (const __attribute__((address_space(1))) unsigned int*)g,
      (__attribute__((address_space(3))) unsigned int*)l, 16, 0, 0);
}

// ---------------------------------------------------------------------------
// JAX threefry2x32 dropout, key=(0,42), partitionable (bit-exact, r1-verified)
// ---------------------------------------------------------------------------
__device__ __forceinline__ uint32_t rotl32(uint32_t x, int r) {
  return (x << r) | (x >> (32 - r));
}
__device__ __forceinline__ bool drop_keep(uint32_t j) {
  const uint32_t k0 = 0u, k1 = 42u, k2 = 0x1BD11BDAu ^ k0 ^ k1;
  uint32_t v0 = 0u + k0;
  uint32_t v1 = j + k1;
#define TF_R(r) { v0 += v1; v1 = rotl32(v1, (r)); v1 ^= v0; }
  TF_R(13) TF_R(15) TF_R(26) TF_R(6)
  v0 += k1; v1 += k2 + 1u;
  TF_R(17) TF_R(29) TF_R(16) TF_R(24)
  v0 += k2; v1 += k0 + 2u;
  TF_R(13) TF_R(15) TF_R(26) TF_R(6)
  v0 += k0; v1 += k1 + 3u;
  TF_R(17) TF_R(29) TF_R(16) TF_R(24)
  v0 += k1; v1 += k2 + 4u;
  TF_R(13) TF_R(15) TF_R(26) TF_R(6)
  v0 += k2; v1 += k0 + 5u;
#undef TF_R
  uint32_t bits = v0 ^ v1;
  float u = __uint_as_float((bits >> 9) | 0x3f800000u) - 1.0f;
  return u < 0.8f;
}

// ---------------------------------------------------------------------------
// prep: fp32 -> fp16 convert (8 elem/thread)
// ---------------------------------------------------------------------------
__global__ __launch_bounds__(256)
void conv16_kernel(const float* __restrict__ src, f16* __restrict__ dst, int n) {
  int i = (blockIdx.x * 256 + threadIdx.x) * 8;
  if (i >= n) return;
  float4 a = *(const float4*)&src[i];
  float4 b = *(const float4*)&src[i + 4];
  f16x8 o;
  o[0] = (f16)a.x; o[1] = (f16)a.y; o[2] = (f16)a.z; o[3] = (f16)a.w;
  o[4] = (f16)b.x; o[5] = (f16)b.y; o[6] = (f16)b.z; o[7] = (f16)b.w;
  *(f16x8*)&dst[i] = o;
}

// x [B][S][D] fp32 -> xT [B][D][S] fp16
__global__ __launch_bounds__(256)
void xt16_kernel(const float* __restrict__ x, f16* __restrict__ xT) {
  const int b = blockIdx.z, sb = blockIdx.x * 32, db = blockIdx.y * 32;
  __shared__ float t[32][33];
  const int tid = threadIdx.x;
  const int r = tid >> 3, c4 = (tid & 7) * 4;
  float4 v = *(const float4*)&x[((size_t)b * S_ + sb + r) * D_ + db + c4];
  t[r][c4] = v.x; t[r][c4 + 1] = v.y; t[r][c4 + 2] = v.z; t[r][c4 + 3] = v.w;
  __syncthreads();
  const int dr = tid >> 3, s4 = (tid & 7) * 4;
  f16x4 o;
#pragma unroll
  for (int j = 0; j < 4; ++j) o[j] = (f16)t[s4 + j][dr];
  *(f16x4*)&xT[((size_t)b * D_ + db + dr) * S_ + sb + s4] = o;
}

// ---------------------------------------------------------------------------
// GEMM1T (fp16 MFMA): scoresT[b, lt+l, st+s] = E[l,:] . x[s,:]  (fp32 out)
// Tile 128l x 128s, BK=32, 4 waves. Coalesced 16-row x 64B chunk staging with
// lane permutation -> kq-major granules (conflict-free b128 frag reads),
// 2-phase double-buffered.
// ALSO: computes the dropout keep-bit mask for this block's 128x128 cell
// tile (64 threefry hashes/thread, 8 per K-iter — hidden under staging
// latency) and writes packed bits: kb[b][l][16 u32 words], word w = q*4 + i,
// bit c*8+j  <->  s = 32*(i*4+c) + 8*q + j.
// Epilogue: per-s column max/expsum over l -> partials.
// ---------------------------------------------------------------------------
__global__ __launch_bounds__(256)
void gemm1t_f16(const f16* __restrict__ eh, const f16* __restrict__ xh,
                float* __restrict__ scoresT, float2* __restrict__ partials,
                uint32_t* __restrict__ kb) {
  __shared__ __align__(16) f16 As[2][4096];  // E tile: granule = c*64+kq'*16+rlow
  __shared__ __align__(16) f16 Bs[2][4096];  // x tile: same layout
  __shared__ float pmaxA[128][2];
  __shared__ float psumA[128][2];

  const int tid = threadIdx.x;
  const int lane = tid & 63, wave = tid >> 6;
  const int b = blockIdx.z, lt = blockIdx.x * 128, st = blockIdx.y * 128;

  const int lm = lane & 15, kq = lane >> 4;
  const int wm = (wave & 1) * 64, wn = (wave >> 1) * 64;
  const int ca = (wave & 1) * 4, cb = (wave >> 1) * 4;  // frag chunk bases

  // staging lane mapping: row = 16c + (lane&15), k-slice = (lane>>4)*8 f16.
  const int srow = lane & 15, sko = (lane >> 4) * 8;
  auto stage = [&](int bi, int k0) {
#pragma unroll
    for (int i = 0; i < 2; ++i) {
      const int c = wave * 2 + i;
      gl16(eh + ((size_t)b * L_ + lt + c * 16 + srow) * D_ + k0 + sko,
           (char*)As[bi] + c * 1024 + lane * 16);
      gl16(xh + ((size_t)b * S_ + st + c * 16 + srow) * D_ + k0 + sko,
           (char*)Bs[bi] + c * 1024 + lane * 16);
    }
  };

  // dropout-mask assignment: thread owns row l = lt + (tid>>1), quarters
  // q0, q0+1 (q0 = (tid&1)*2); per K-iter t: q = q0 + (t>>2), c = t&3.
  const int q0 = (tid & 1) * 2;
  const int ml = lt + (tid >> 1);
  uint32_t wlo = 0, whi = 0;

  f32x4 acc[4][4] = {};

  stage(0, 0);
  __syncthreads();
  int bi = 0;
  for (int t = 0; t < 8; ++t) {
    if (t < 7) stage(bi ^ 1, (t + 1) * 32);

    // ---- 8 dropout hashes (fills the staging-latency window) ----
    {
      const int c = t & 3, q = q0 + (t >> 2);
      const uint32_t base =
          (uint32_t)(b * S_ + st + 32 * c + 8 * q) * (uint32_t)L_ +
          (uint32_t)ml;
      uint32_t byte = 0;
#pragma unroll
      for (int j = 0; j < 8; ++j)
        byte |= (uint32_t)drop_keep(base + (uint32_t)j * L_) << j;
      if (t < 4) wlo |= byte << (8 * c);
      else       whi |= byte << (8 * c);
    }

    f16x8 fa[4], fb[4];
#pragma unroll
    for (int mi = 0; mi < 4; ++mi)
      fa[mi] = *(const f16x8*)&As[bi][((ca + mi) * 64 + kq * 16 + lm) * 8];
#pragma unroll
    for (int ni = 0; ni < 4; ++ni)
      fb[ni] = *(const f16x8*)&Bs[bi][((cb + ni) * 64 + kq * 16 + lm) * 8];
#pragma unroll
    for (int mi = 0; mi < 4; ++mi)
#pragma unroll
      for (int ni = 0; ni < 4; ++ni)
        acc[mi][ni] = __builtin_amdgcn_mfma_f32_16x16x32_f16(
            fa[mi], fb[ni], acc[mi][ni], 0, 0, 0);
    __syncthreads();
    bi ^= 1;
  }

  // ---- keep-bit store: words w = q*4 + blockIdx.y, q in {q0, q0+1} ----
  {
    uint32_t* kp = kb + ((size_t)b * L_ + ml) * 16 + blockIdx.y;
    kp[q0 * 4] = wlo;
    kp[(q0 + 1) * 4] = whi;
  }

  // ---- scoresT store. D: row l = kq*4 + r (within 16-tile), col s = lm ----
#pragma unroll
  for (int mi = 0; mi < 4; ++mi)
#pragma unroll
    for (int ni = 0; ni < 4; ++ni) {
      const int l0 = wm + mi * 16 + kq * 4;
      const int s = wn + ni * 16 + lm;
      float* sp = scoresT + ((size_t)b * L_ + lt + l0) * S_ + st + s;
#pragma unroll
      for (int r = 0; r < 4; ++r) sp[(size_t)r * S_] = acc[mi][ni][r];
    }

  // ---- per-s column max over this wave's 64 l-rows ----
  float cmax[4];
#pragma unroll
  for (int ni = 0; ni < 4; ++ni) {
    float v = acc[0][ni][0];
#pragma unroll
    for (int mi = 0; mi < 4; ++mi)
#pragma unroll
      for (int r = 0; r < 4; ++r) v = fmaxf(v, acc[mi][ni][r]);
    cmax[ni] = v;
  }
#pragma unroll
  for (int ni = 0; ni < 4; ++ni) {
    cmax[ni] = fmaxf(cmax[ni], __shfl_xor(cmax[ni], 16, 64));
    cmax[ni] = fmaxf(cmax[ni], __shfl_xor(cmax[ni], 32, 64));
  }
  if (kq == 0) {
#pragma unroll
    for (int ni = 0; ni < 4; ++ni) pmaxA[wn + ni * 16 + lm][wave & 1] = cmax[ni];
  }
  __syncthreads();
  float colm[4];
#pragma unroll
  for (int ni = 0; ni < 4; ++ni) {
    const int s = wn + ni * 16 + lm;
    colm[ni] = fmaxf(pmaxA[s][0], pmaxA[s][1]);
  }
  float psum[4] = {};
#pragma unroll
  for (int ni = 0; ni < 4; ++ni)
#pragma unroll
    for (int mi = 0; mi < 4; ++mi)
#pragma unroll
      for (int r = 0; r < 4; ++r)
        psum[ni] += __expf(acc[mi][ni][r] - colm[ni]);
#pragma unroll
  for (int ni = 0; ni < 4; ++ni) {
    psum[ni] += __shfl_xor(psum[ni], 16, 64);
    psum[ni] += __shfl_xor(psum[ni], 32, 64);
  }
  if (kq == 0) {
#pragma unroll
    for (int ni = 0; ni < 4; ++ni) psumA[wn + ni * 16 + lm][wave & 1] = psum[ni];
  }
  __syncthreads();
  if (tid < 128) {
    float m = fmaxf(pmaxA[tid][0], pmaxA[tid][1]);
    float Z = psumA[tid][0] + psumA[tid][1];
    partials[((size_t)b * 64 + blockIdx.x) * S_ + st + tid] = make_float2(m, Z);
  }
}

// ---------------------------------------------------------------------------
// combine partial (m,Z) over 64 l-tiles -> stats (m, factor)
// ---------------------------------------------------------------------------
__global__ __launch_bounds__(256)
void combine_kernel(const float2* __restrict__ partials,
                    const int* __restrict__ mask, float2* __restrict__ stats) {
  const int idx = blockIdx.x * 256 + threadIdx.x;  // b*S + si
  const int b = idx / S_, si = idx - b * S_;
  float m = -3.402823466e38f, Z = 0.f;
  for (int t = 0; t < 64; ++t) {
    float2 p = partials[((size_t)b * 64 + t) * S_ + si];
    if (p.x > m) {
      Z = Z * __expf(m - p.x) + p.y;
      m = p.x;
    } else {
      Z += p.y * __expf(p.x - m);
    }
  }
  float f = (mask[idx] != 0) ? (1.25f / Z) : 0.0f;
  stats[idx] = make_float2(m, f);
}

// ---------------------------------------------------------------------------
// GEMM2 fused (fp16 MFMA, full-D tile, K = S = 512):
//   out[b, lt+l, d] = sum_s P(s, lt+l) * x[s, d]
// P from scoresT (per-lane f32x4 pair straight from global, prefetched) +
// precomputed keep bits (one uint4 per lane for the whole kernel).
// No threefry here — VALU collapses; kernel is scoresT/out BW-bound.
// Bs (xT): double-buffered, coalesced staging, conflict-free frag reads.
// K-loop statically unrolled 4x4 so keep-words are register-indexed.
// ---------------------------------------------------------------------------
__global__ __launch_bounds__(512)
void gemm2_fused(const float* __restrict__ scoresT, const f16* __restrict__ xT,
                 const float2* __restrict__ stats,
                 const uint32_t* __restrict__ kb, float* __restrict__ out) {
  __shared__ __align__(16) f16 Bs[2][8192];    // xT tile: granule = c*64+kq'*16+dlow
  __shared__ float2 stat_s[S_];                // 4 KB, full-S stats

  const int tid = threadIdx.x;
  const int lane = tid & 63, wave = tid >> 6;
  const int b = blockIdx.z, lt = blockIdx.x * 128;

  stat_s[tid] = stats[b * S_ + tid];  // covered by prologue barrier

  const int lm = lane & 15, kq = lane >> 4;
  const int l_loc = wave * 16 + lm;  // 0..127

  // Bs staging: chunk c (0..15) = d-rows [16c,16c+16). lane -> d = 16c+(lane&15),
  // s-slice = (lane>>4)*8 f16. Wave w stages chunks {2w, 2w+1}.
  const int srow = lane & 15, sko = (lane >> 4) * 8;
  const size_t xb_base = (size_t)b * D_ * S_;
  auto stage = [&](int bi, int k0) {
#pragma unroll
    for (int i = 0; i < 2; ++i) {
      const int c = wave * 2 + i;
      gl16(xT + xb_base + (size_t)(c * 16 + srow) * S_ + k0 + sko,
           (char*)Bs[bi] + c * 1024 + lane * 16);
    }
  };

  // per-lane scores row pointer: contiguous 32 B (8 floats) per chunk
  const float* srowp =
      scoresT + ((size_t)b * L_ + lt + l_loc) * S_ + kq * 8;

  // keep bits: lane's quarter q = kq -> words q*4 + (0..3), one uint4.
  const uint4 kwv = *(const uint4*)(kb + ((size_t)b * L_ + lt + l_loc) * 16 +
                                    kq * 4);
  const uint32_t kwa[4] = {kwv.x, kwv.y, kwv.z, kwv.w};

  f32x4 acc[16] = {};

  f32x4 sv0 = *(const f32x4*)&srowp[0];
  f32x4 sv1 = *(const f32x4*)&srowp[4];
  stage(0, 0);
  __syncthreads();
#pragma unroll
  for (int kg = 0; kg < 4; ++kg) {
#pragma unroll
    for (int c = 0; c < 4; ++c) {
      const int kk = kg * 4 + c;
      const int k0 = kk * 32;
      const int bi = kk & 1;
      f32x4 nv0, nv1;
      if (kk < 15) {
        stage(bi ^ 1, k0 + 32);
        nv0 = *(const f32x4*)&srowp[k0 + 32];
        nv1 = *(const f32x4*)&srowp[k0 + 36];
      }

      // ---- P values for s = k0 + kq*8 + (0..7) ----
      float pv[8];
#pragma unroll
      for (int j = 0; j < 4; ++j) {
        const float2 mf = stat_s[k0 + kq * 8 + j];
        pv[j] = __expf(sv0[j] - mf.x) * mf.y;
      }
#pragma unroll
      for (int j = 0; j < 4; ++j) {
        const float2 mf = stat_s[k0 + kq * 8 + 4 + j];
        pv[4 + j] = __expf(sv1[j] - mf.x) * mf.y;
      }
      const uint32_t mbyte = (kwa[kg] >> (c * 8)) & 0xffu;
      f16x8 fa;
#pragma unroll
      for (int j = 0; j < 8; ++j)
        fa[j] = ((mbyte >> j) & 1u) ? (f16)pv[j] : (f16)0.f;

#pragma unroll
      for (int ni = 0; ni < 16; ++ni) {
        const f16x8 fb = *(const f16x8*)&Bs[bi][(ni * 64 + kq * 16 + lm) * 8];
        acc[ni] = __builtin_amdgcn_mfma_f32_16x16x32_f16(fa, fb, acc[ni], 0, 0, 0);
      }
      __syncthreads();
      if (kk < 15) { sv0 = nv0; sv1 = nv1; }
    }
  }

  // ---- epilogue. C/D: col = lane&15 (d), row = kq*4 + reg (l within 16) ----
#pragma unroll
  for (int ni = 0; ni < 16; ++ni) {
    const int n = ni * 16 + lm;
    float* op = out + ((size_t)b * L_ + lt + wave * 16 + kq * 4) * D_ + n;
#pragma unroll
    for (int r = 0; r < 4; ++r) op[(size_t)r * D_] = acc[ni][r];
  }
}

// ---------------------------------------------------------------------------
extern "C" void kernel_launch(void* const* d_in, const int* in_sizes, int n_in,
                              void* d_out, int out_size, void* d_ws, size_t ws_size,
                              hipStream_t stream) {
  const float* x = (const float*)d_in[0];
  const int* mask = (const int*)d_in[1];
  const float* E = (const float*)d_in[2];
  float* out = (float*)d_out;

  char* ws = (char*)d_ws;
  const size_t nE = (size_t)B_ * L_ * D_;  // 33.5M
  const size_t nX = (size_t)B_ * S_ * D_;  // 2.1M
  size_t o = 0;
  f16* Eh = (f16*)(ws + o); o += nE * 2;                                // 67 MB
  f16* Xh = (f16*)(ws + o); o += nX * 2;                                // 4 MB
  f16* XT = (f16*)(ws + o); o += nX * 2;                                // 4 MB
  float2* stats = (float2*)(ws + o); o += (size_t)B_ * S_ * 8;          // 64 KB
  float2* partials = (float2*)(ws + o); o += (size_t)B_ * 64 * S_ * 8;  // 4 MB
  uint32_t* kb = (uint32_t*)(ws + o); o += (size_t)B_ * L_ * 16 * 4;    // 8.4 MB
  float* scoresT = (float*)(ws + o);  // [B][L][S] fp32, 268 MB (total ~352 MB)

  conv16_kernel<<<dim3((unsigned)(nE / 8 / 256)), 256, 0, stream>>>(E, Eh, (int)nE);
  conv16_kernel<<<dim3((unsigned)(nX / 8 / 256)), 256, 0, stream>>>(x, Xh, (int)nX);
  xt16_kernel<<<dim3(S_ / 32, D_ / 32, B_), 256, 0, stream>>>(x, XT);

  gemm1t_f16<<<dim3(L_ / 128, S_ / 128, B_), 256, 0, stream>>>(
      Eh, Xh, scoresT, partials, kb);
  combine_kernel<<<dim3(B_ * S_ / 256), 256, 0, stream>>>(partials, mask, stats);
  gemm2_fused<<<dim3(L_ / 128, 1, B_), 512, 0, stream>>>(scoresT, XT, stats, kb, out);
}